// Round 9
// baseline (967.496 us; speedup 1.0000x reference)
//
#include <hip/hip_runtime.h>
#include <math.h>
#include <stdint.h>

#define BB  4
#define TT  2048
#define DD  1024
#define NNq 4096
#define BT  (BB*TT)       // 8192
#define NCH 16            // scan chunks along T
#define TCH (TT/NCH)      // 128 timesteps per chunk

typedef _Float16 f16;
typedef __attribute__((ext_vector_type(8))) _Float16 half8;
typedef __attribute__((ext_vector_type(4))) float f32x4;

__device__ __forceinline__ float sigmoid_f(float x){ return 1.f/(1.f+__expf(-x)); }
__device__ __forceinline__ float tanh_f(float x){
  float cx = fminf(fmaxf(x,-15.f),15.f);
  float e  = __expf(2.f*cx);
  return (e-1.f)/(e+1.f);
}
__device__ __forceinline__ float softplus_f(float x){
  return (x>15.f)? x : __logf(1.f+__expf(x));
}

// ---------------- prep: f32 -> f16 cast (vectorized) ----------------
__global__ __launch_bounds__(256) void cast_f16_k(const float* __restrict__ src,
                                                  f16* __restrict__ dst){
  size_t i = ((size_t)blockIdx.x*256 + threadIdx.x)*4;
  float4 v = *(const float4*)(src + i);
  union { f16 h[4]; uint2 u; } o;
  o.h[0]=(f16)v.x; o.h[1]=(f16)v.y; o.h[2]=(f16)v.z; o.h[3]=(f16)v.w;
  *(uint2*)(dst + i) = o.u;
}

// ---------------- prep: transpose + cast  src[R][C] f32 -> dst[C][R] f16 ----
__global__ __launch_bounds__(256) void transpose_cast_k(const float* __restrict__ src,
                                                        f16* __restrict__ dst,
                                                        int R, int C){
  __shared__ float tile[32][33];
  int c0 = blockIdx.x*32, r0 = blockIdx.y*32;
  int tx = threadIdx.x, ty = threadIdx.y;
  #pragma unroll
  for (int i=0;i<4;i++){ int r = ty + i*8; tile[r][tx] = src[(size_t)(r0+r)*C + c0+tx]; }
  __syncthreads();
  #pragma unroll
  for (int i=0;i<4;i++){ int c = ty + i*8; dst[(size_t)(c0+c)*R + r0+tx] = (f16)tile[tx][c]; }
}

// ---------------- fp16 MFMA GEMM: C[.][.] = A[rows m][K] * Bt[rows n][K]^T ---
// 128x128 tile, BK=64, 4 waves (2x2), each wave 64x64 via 4x4 frags of 16x16x32.
// Reg-staged global->LDS (no global_load_lds this round; addrspace-cast risk).
// Strided: lda/ldb/ldc element strides. Grid: x = n-tiles, y = m-tiles.
template<int OUT_F32>
__global__ __launch_bounds__(256)
void gemm_bt(const f16* __restrict__ A, int lda,
             const f16* __restrict__ Bt, int ldb,
             void* __restrict__ Cout, int ldc, int K)
{
  __shared__ f16 lsA[128*64];
  __shared__ f16 lsB[128*64];
  const int tid  = threadIdx.x;
  const int lane = tid & 63;
  const int wave = tid >> 6;
  const int wm = wave >> 1, wn = wave & 1;
  const int m0 = blockIdx.y * 128;
  const int n0 = blockIdx.x * 128;

  const f16* Ag = A  + (size_t)m0 * lda;
  const f16* Bg = Bt + (size_t)n0 * ldb;

  f32x4 acc[4][4] = {};

  for (int k0 = 0; k0 < K; k0 += 64) {
    // reg-stage (issue loads before the barrier; T14-lite overlap, m249)
    half8 ra[4], rb[4];
    #pragma unroll
    for (int i = 0; i < 4; i++) {
      const int j   = i*256 + tid;
      const int row = j >> 3;        // 8 chunks of 16B per 64-elem row
      const int ce  = (j & 7) * 8;   // element offset within row
      ra[i] = *(const half8*)(Ag + (size_t)row*lda + k0 + ce);
      rb[i] = *(const half8*)(Bg + (size_t)row*ldb + k0 + ce);
    }
    __syncthreads();                 // previous iter's compute done reading LDS
    #pragma unroll
    for (int i = 0; i < 4; i++) {
      const int j = i*256 + tid;
      *(half8*)&lsA[j*8] = ra[i];
      *(half8*)&lsB[j*8] = rb[i];
    }
    __syncthreads();
    #pragma unroll
    for (int ks = 0; ks < 2; ks++) {
      const int kk = ks*32 + (lane>>4)*8;
      half8 af[4], bfr[4];
      #pragma unroll
      for (int mi=0; mi<4; mi++)
        af[mi] = *(const half8*)&lsA[(wm*64 + mi*16 + (lane&15))*64 + kk];
      #pragma unroll
      for (int ni=0; ni<4; ni++)
        bfr[ni] = *(const half8*)&lsB[(wn*64 + ni*16 + (lane&15))*64 + kk];
      #pragma unroll
      for (int mi=0; mi<4; mi++)
        #pragma unroll
        for (int ni=0; ni<4; ni++)
          acc[mi][ni] = __builtin_amdgcn_mfma_f32_16x16x32_f16(af[mi], bfr[ni], acc[mi][ni], 0, 0, 0);
    }
  }

  // C/D layout (m89-verified): col = lane&15, row = (lane>>4)*4 + r
  const int crow = m0 + wm*64 + (lane>>4)*4;
  const int ccol = n0 + wn*64 + (lane&15);
  #pragma unroll
  for (int mi=0; mi<4; mi++)
    #pragma unroll
    for (int ni=0; ni<4; ni++)
      #pragma unroll
      for (int r=0; r<4; r++) {
        size_t idx = (size_t)(crow + mi*16 + r) * ldc + (ccol + ni*16);
        if (OUT_F32) ((float*)Cout)[idx] = acc[mi][ni][r];
        else         ((f16*)Cout)[idx]   = (f16)acc[mi][ni][r];
      }
}

// ---------------- scan phase A: per-(b,n,chunk) aggregates --------------
// zg,zd: per-chunk buffers, row stride NC. zr: P-full slice, row stride NNq.
// Alog/bd/Agg pointers pre-offset by ncol0; Agg row stride NNq.
__global__ __launch_bounds__(256) void scan_agg_k(
    const f16* __restrict__ zg, const f16* __restrict__ zr, const f16* __restrict__ zd,
    const float* __restrict__ Alog, const float* __restrict__ bdelta,
    float* __restrict__ AggA, float* __restrict__ AggB, int NC)
{
  const int nb = NC >> 8;                 // NC/256, NC in {256..4096}
  const int bx = blockIdx.x;
  const int nl = (bx % nb)*256 + threadIdx.x;
  const int c  = (bx / nb) % NCH;
  const int b  = bx / (nb*NCH);
  const float An = -__expf(Alog[nl]);
  const float bd = bdelta[nl];
  float pA = 1.f, pB = 0.f;
  const size_t rbase = (size_t)(b*TT + c*TCH);
  #pragma unroll 4
  for (int t=0; t<TCH; ++t) {
    size_t rr = rbase + t;
    float g  = (float)zg[rr*NC  + nl];
    float r  = (float)zr[rr*NNq + nl];
    float dz = (float)zd[rr*NC  + nl] + bd;
    float d  = __expf(An * softplus_f(dz));
    float u  = (1.f-d) * sigmoid_f(g) * tanh_f(r);
    pA *= d;
    pB = fmaf(d, pB, u);
  }
  size_t o = ((size_t)(b*NCH + c))*NNq + nl;
  AggA[o] = pA;
  AggB[o] = pB;
}

// ---------------- scan phase B: chunk-level scan + final state ----------
// All pointers pre-offset by ncol0; row strides NNq.
__global__ __launch_bounds__(256) void scan_mid_k(
    const float* __restrict__ AggA, const float* __restrict__ AggB,
    const float* __restrict__ state0, float* __restrict__ sIn,
    float* __restrict__ fstate, int NC)
{
  int gi = blockIdx.x*256 + threadIdx.x;   // 0 .. BB*NC
  int b  = gi / NC, nl = gi % NC;
  float s = state0[(size_t)b*NNq + nl];
  #pragma unroll
  for (int c=0; c<NCH; ++c) {
    size_t o = ((size_t)(b*NCH + c))*NNq + nl;
    sIn[o] = s;
    s = fmaf(AggA[o], s, AggB[o]);
  }
  fstate[(size_t)b*NNq + nl] = s;
}

// ---------------- scan phase C: apply + mix + modulate -> P fp16 (in place) --
// zr/P alias (same-index read-before-write) -> no __restrict__ on them.
__global__ __launch_bounds__(256) void scan_apply_k(
    const f16* zr, const f16* __restrict__ zg, const f16* __restrict__ zm,
    const f16* __restrict__ zd,
    const float* __restrict__ Alog, const float* __restrict__ bdelta,
    const float* __restrict__ swl, const float* __restrict__ sIn,
    f16* P, int NC)
{
  const int nb = NC >> 8;
  const int bx = blockIdx.x;
  const int nl = (bx % nb)*256 + threadIdx.x;
  const int c  = (bx / nb) % NCH;
  const int b  = bx / (nb*NCH);
  const float An = -__expf(Alog[nl]);
  const float bd = bdelta[nl];
  const float sw = sigmoid_f(swl[nl]);
  float s = sIn[((size_t)(b*NCH + c))*NNq + nl];
  const size_t rbase = (size_t)(b*TT + c*TCH);
  for (int t=0; t<TCH; ++t) {
    size_t rr = rbase + t;
    float r  = (float)zr[rr*NNq + nl];
    float g  = (float)zg[rr*NC  + nl];
    float m  = (float)zm[rr*NC  + nl];
    float dz = (float)zd[rr*NC  + nl] + bd;
    float d  = __expf(An * softplus_f(dz));
    float u  = (1.f-d) * sigmoid_f(g) * tanh_f(r);
    s = fmaf(d, s, u);
    float gel = 0.5f*r*(1.f+erff(r*0.70710678118654752f));
    float mod = tanh_f(m);
    float op  = ((1.f-sw)*gel + sw*s)*(1.f+mod);
    P[rr*NNq + nl] = (f16)op;
  }
}

extern "C" void kernel_launch(void* const* d_in, const int* in_sizes, int n_in,
                              void* d_out, int out_size, void* d_ws, size_t ws_size,
                              hipStream_t stream)
{
  const float* x      = (const float*)d_in[0];
  const float* state0 = (const float*)d_in[1];
  const float* Wmain  = (const float*)d_in[2];
  const float* Wgate  = (const float*)d_in[3];
  const float* Wmod   = (const float*)d_in[4];
  const float* Wdelta = (const float*)d_in[5];
  const float* bdelta = (const float*)d_in[6];
  const float* Wout   = (const float*)d_in[7];
  const float* Alog   = (const float*)d_in[8];
  const float* swl    = (const float*)d_in[9];

  auto al = [](size_t v)->size_t { return (v + 255) & ~(size_t)255; };
  const size_t sz_xb  = al((size_t)BT*DD*2);
  const size_t sz_wt  = al((size_t)NNq*DD*2);   // each of 4 proj weights (transposed)
  const size_t sz_wto = al((size_t)DD*NNq*2);
  const size_t sz_P   = al((size_t)BT*NNq*2);
  const size_t sz_agg = al((size_t)BB*NCH*NNq*4);
  const size_t fixed  = sz_xb + 4*sz_wt + sz_wto + sz_P + 3*sz_agg;

  // pick largest N-chunk (smallest NCC) whose footprint fits ws_size
  int NCC = 16;
  {
    const int cand[5] = {1,2,4,8,16};
    for (int i=0;i<5;i++){
      size_t zchunk = al((size_t)BT*(NNq/cand[i])*2);
      if (fixed + 3*zchunk <= ws_size) { NCC = cand[i]; break; }
    }
  }
  const int NC = NNq / NCC;
  const size_t sz_z = al((size_t)BT*NC*2);

  char* ws = (char*)d_ws;
  size_t off = 0;
  auto alloc = [&](size_t bytes)->void* { void* p = ws + off; off += bytes; return p; };
  f16*   xb   = (f16*)alloc(sz_xb);
  f16*   wt0  = (f16*)alloc(sz_wt);
  f16*   wt1  = (f16*)alloc(sz_wt);
  f16*   wt2  = (f16*)alloc(sz_wt);
  f16*   wt3  = (f16*)alloc(sz_wt);
  f16*   wto  = (f16*)alloc(sz_wto);
  f16*   P    = (f16*)alloc(sz_P);     // z_raw written here (strided), then out_pre in place
  float* AggA = (float*)alloc(sz_agg);
  float* AggB = (float*)alloc(sz_agg);
  float* sIn  = (float*)alloc(sz_agg);
  f16*   z1   = (f16*)alloc(sz_z);     // gate  (per-chunk)
  f16*   z2   = (f16*)alloc(sz_z);     // mod   (per-chunk)
  f16*   z3   = (f16*)alloc(sz_z);     // delta (per-chunk)

  float* fstate = (float*)d_out + (size_t)BT*DD;

  // prep
  cast_f16_k<<<(BT*DD)/1024, 256, 0, stream>>>(x, xb);
  transpose_cast_k<<<dim3(NNq/32, DD/32), dim3(32,8), 0, stream>>>(Wmain,  wt0, DD, NNq);
  transpose_cast_k<<<dim3(NNq/32, DD/32), dim3(32,8), 0, stream>>>(Wgate,  wt1, DD, NNq);
  transpose_cast_k<<<dim3(NNq/32, DD/32), dim3(32,8), 0, stream>>>(Wmod,   wt2, DD, NNq);
  transpose_cast_k<<<dim3(NNq/32, DD/32), dim3(32,8), 0, stream>>>(Wdelta, wt3, DD, NNq);
  transpose_cast_k<<<dim3(DD/32, NNq/32), dim3(32,8), 0, stream>>>(Wout,   wto, NNq, DD);

  const dim3 gz(NC/128, BT/128);
  for (int cc = 0; cc < NCC; ++cc) {
    const int n0 = cc * NC;
    // projections for this N-chunk (raw -> P slice, others -> chunk buffers)
    gemm_bt<0><<<gz, 256, 0, stream>>>(xb, DD, wt0 + (size_t)n0*DD, DD, P + n0, NNq, DD);
    gemm_bt<0><<<gz, 256, 0, stream>>>(xb, DD, wt1 + (size_t)n0*DD, DD, z1, NC, DD);
    gemm_bt<0><<<gz, 256, 0, stream>>>(xb, DD, wt2 + (size_t)n0*DD, DD, z2, NC, DD);
    gemm_bt<0><<<gz, 256, 0, stream>>>(xb, DD, wt3 + (size_t)n0*DD, DD, z3, NC, DD);
    // chunked scan over T
    scan_agg_k<<<BB*NCH*(NC/256), 256, 0, stream>>>(z1, P + n0, z3,
        Alog + n0, bdelta + n0, AggA + n0, AggB + n0, NC);
    scan_mid_k<<<(BB*NC)/256, 256, 0, stream>>>(AggA + n0, AggB + n0,
        state0 + n0, sIn + n0, fstate + n0, NC);
    scan_apply_k<<<BB*NCH*(NC/256), 256, 0, stream>>>(P + n0, z1, z2, z3,
        Alog + n0, bdelta + n0, swl + n0, sIn + n0, P + n0, NC);
  }

  // output GEMM: out[BT][DD] f32 = P[BT][NNq] * Wout^T   (wto is [DD][NNq])
  gemm_bt<1><<<dim3(DD/128, BT/128), 256, 0, stream>>>(P, NNq, wto, NNq, d_out, DD, NNq);
}